// Round 10
// baseline (452.292 us; speedup 1.0000x reference)
//
#include <hip/hip_runtime.h>
#include <hip/hip_bf16.h>
#include <math.h>

#define D_MODEL 1024
#define SEQ     1024
#define NHEADS  16
#define NKVH    4
#define HDIM    64
#define NEXP    64
#define TOPK    6
#define HEXP    512
#define EPS     1e-5f
#define MAXTILES 120   // 112 expert tiles max + 8 shared-expert tiles

typedef __attribute__((ext_vector_type(8))) short bf16x8;
typedef __attribute__((ext_vector_type(4))) float f32x4;

struct bfrag2 { bf16x8 hi, lo; };
struct f32x8r { float v[8]; };

__device__ __forceinline__ unsigned rne1(float a) {
  union { float f; unsigned u; } x; x.f = a;
  return (x.u + 0x7fffu + ((x.u >> 16) & 1u)) >> 16;
}
__device__ __forceinline__ float frombf(unsigned h) {
  union { float f; unsigned u; } x; x.u = h << 16; return x.f;
}
__device__ __forceinline__ void split_pack(float a, float b, unsigned& hi, unsigned& lo) {
  unsigned ha = rne1(a), hb = rne1(b);
  hi = ha | (hb << 16);
  lo = rne1(a - frombf(ha)) | (rne1(b - frombf(hb)) << 16);
}
__device__ __forceinline__ unsigned pk2bf(float a, float b) {
  return rne1(a) | (rne1(b) << 16);
}

__device__ __forceinline__ f32x4 mfma16(bf16x8 a, bf16x8 b, f32x4 c) {
  return __builtin_amdgcn_mfma_f32_16x16x32_bf16(a, b, c, 0, 0, 0);
}
__device__ __forceinline__ f32x4 mfma_sp(bf16x8 ah, bf16x8 al, const bfrag2& b, f32x4 c) {
  c = mfma16(ah, b.hi, c);
  c = mfma16(ah, b.lo, c);
  c = mfma16(al, b.hi, c);
  return c;
}

// barrier WITHOUT the compiler's vmcnt(0) drain: LDS ordered, global loads stay in flight
__device__ __forceinline__ void barrier_nv() {
  asm volatile("s_waitcnt lgkmcnt(0)" ::: "memory");
  __builtin_amdgcn_s_barrier();
}

__device__ __forceinline__ f32x8r loadraw8(const float* __restrict__ p, int ld) {
  f32x8r r;
#pragma unroll
  for (int i = 0; i < 8; i++) r.v[i] = p[(size_t)ld * i];
  return r;
}
__device__ __forceinline__ bfrag2 cvt_bf2(const f32x8r& f) {
  union { bf16x8 v; unsigned u[4]; } H, L;
  split_pack(f.v[0], f.v[1], H.u[0], L.u[0]);
  split_pack(f.v[2], f.v[3], H.u[1], L.u[1]);
  split_pack(f.v[4], f.v[5], H.u[2], L.u[2]);
  split_pack(f.v[6], f.v[7], H.u[3], L.u[3]);
  bfrag2 r; r.hi = H.v; r.lo = L.v; return r;
}

// B-fragment read from LDS [32][RL] ushort; RL chosen conflict-free
template<int RL>
__device__ __forceinline__ bf16x8 bfrag_lds(const ushort* __restrict__ B, int akb, int c) {
  union { bf16x8 v; ushort s[8]; } r;
#pragma unroll
  for (int j = 0; j < 8; j++) r.s[j] = B[(akb + j) * RL + c];
  return r.v;
}

// ---------------- rmsnorm over D=1024 (+ optional bf16 copy) ----------------
__global__ __launch_bounds__(256) void rmsnorm_k(const float* __restrict__ x,
    const float* __restrict__ w, float* __restrict__ out, ushort* __restrict__ outb) {
  int t = blockIdx.x;
  const float4* xr = (const float4*)(x + (size_t)t * D_MODEL);
  float4 v = xr[threadIdx.x];
  float ss = v.x*v.x + v.y*v.y + v.z*v.z + v.w*v.w;
  for (int off = 32; off; off >>= 1) ss += __shfl_xor(ss, off);
  __shared__ float red[4];
  if ((threadIdx.x & 63) == 0) red[threadIdx.x >> 6] = ss;
  __syncthreads();
  float tot = red[0] + red[1] + red[2] + red[3];
  float inv = rsqrtf(tot * (1.f / D_MODEL) + EPS);
  float4 wv = ((const float4*)w)[threadIdx.x];
  float4 o;
  o.x = v.x * inv * wv.x; o.y = v.y * inv * wv.y;
  o.z = v.z * inv * wv.z; o.w = v.w * inv * wv.w;
  ((float4*)(out + (size_t)t * D_MODEL))[threadIdx.x] = o;
  if (outb) {
    uint2 b;
    b.x = pk2bf(o.x, o.y); b.y = pk2bf(o.z, o.w);
    *(uint2*)(outb + (size_t)t * D_MODEL + threadIdx.x * 4) = b;
  }
}

// ---------------- dense split-bf16 MFMA GEMM, depth-2 pipeline, relaxed barrier ----
__global__ __launch_bounds__(256) void mfma_gemm_k(const float* __restrict__ A,
    const float* __restrict__ B, float* __restrict__ C, float* __restrict__ C2,
    const float* __restrict__ resid, int N, int K) {
  __shared__ short Ah[2][16][40];
  __shared__ short Al[2][16][40];
  int bm = blockIdx.y << 4, bn = blockIdx.x << 7;
  int tid = threadIdx.x, wv = tid >> 6, lane = tid & 63;
  int m_ = tid >> 4, k_ = (tid & 15) << 1;
  int arow = lane & 15, akb = (lane >> 4) << 3;
  int c0 = bn + wv * 32 + arow;
  const float* ar = A + (size_t)(bm + m_) * K + k_;
  {
    float2 a0 = *(const float2*)ar;
    unsigned hi, lo; split_pack(a0.x, a0.y, hi, lo);
    *(unsigned*)&Ah[0][m_][k_] = hi;
    *(unsigned*)&Al[0][m_][k_] = lo;
  }
  float2 aO = *(const float2*)(ar + 32);
  float2 aE;
  f32x8r bE0 = loadraw8(B + (size_t)akb * N + c0, N);
  f32x8r bE1 = loadraw8(B + (size_t)akb * N + c0 + 16, N);
  f32x8r bO0 = loadraw8(B + (size_t)(32 + akb) * N + c0, N);
  f32x8r bO1 = loadraw8(B + (size_t)(32 + akb) * N + c0 + 16, N);
  __syncthreads();
  f32x4 acc0 = {0.f,0.f,0.f,0.f}, acc1 = {0.f,0.f,0.f,0.f};
  for (int k0 = 0; k0 < K; k0 += 64) {
    { // even
      int kp = (k0 + 64 < K) ? k0 + 64 : 0;
      f32x8r n0 = loadraw8(B + (size_t)(kp + akb) * N + c0, N);
      f32x8r n1 = loadraw8(B + (size_t)(kp + akb) * N + c0 + 16, N);
      float2 an = *(const float2*)(ar + kp);
      bfrag2 f0 = cvt_bf2(bE0), f1 = cvt_bf2(bE1);
      bf16x8 ah = *(const bf16x8*)&Ah[0][arow][akb];
      bf16x8 al = *(const bf16x8*)&Al[0][arow][akb];
      acc0 = mfma_sp(ah, al, f0, acc0);
      acc1 = mfma_sp(ah, al, f1, acc1);
      unsigned hi, lo; split_pack(aO.x, aO.y, hi, lo);
      *(unsigned*)&Ah[1][m_][k_] = hi;
      *(unsigned*)&Al[1][m_][k_] = lo;
      barrier_nv();
      bE0 = n0; bE1 = n1; aE = an;
    }
    { // odd
      int kp = (k0 + 96 < K) ? k0 + 96 : 0;
      f32x8r n0 = loadraw8(B + (size_t)(kp + akb) * N + c0, N);
      f32x8r n1 = loadraw8(B + (size_t)(kp + akb) * N + c0 + 16, N);
      float2 an = *(const float2*)(ar + kp);
      bfrag2 f0 = cvt_bf2(bO0), f1 = cvt_bf2(bO1);
      bf16x8 ah = *(const bf16x8*)&Ah[1][arow][akb];
      bf16x8 al = *(const bf16x8*)&Al[1][arow][akb];
      acc0 = mfma_sp(ah, al, f0, acc0);
      acc1 = mfma_sp(ah, al, f1, acc1);
      unsigned hi, lo; split_pack(aE.x, aE.y, hi, lo);
      *(unsigned*)&Ah[0][m_][k_] = hi;
      *(unsigned*)&Al[0][m_][k_] = lo;
      barrier_nv();
      bO0 = n0; bO1 = n1; aO = an;
    }
  }
  int r0 = (lane >> 4) << 2;
#pragma unroll
  for (int ri = 0; ri < 4; ri++) {
    int row = bm + r0 + ri;
    size_t o0 = (size_t)row * N + c0;
    float v0 = acc0[ri], v1 = acc1[ri];
    if (resid) { v0 += resid[o0]; v1 += resid[o0 + 16]; }
    C[o0] = v0; C[o0 + 16] = v1;
    if (C2) { C2[o0] = v0; C2[o0 + 16] = v1; }
  }
}

// ---------------- per-head rmsnorm + RoPE ----------------
__global__ __launch_bounds__(64) void qknorm_rope_k(float* __restrict__ qb,
    float* __restrict__ kb, const float* __restrict__ qw, const float* __restrict__ kw,
    const float* __restrict__ fcos, const float* __restrict__ fsin) {
  int t = blockIdx.x, hid = blockIdx.y, lane = threadIdx.x;
  float* p; const float* w;
  if (hid < NHEADS) { p = qb + (size_t)t * (NHEADS*HDIM) + hid * HDIM; w = qw; }
  else              { p = kb + (size_t)t * (NKVH*HDIM) + (hid - NHEADS) * HDIM; w = kw; }
  float v = p[lane];
  float ss = v * v;
  for (int off = 32; off; off >>= 1) ss += __shfl_xor(ss, off);
  float vn = v * rsqrtf(ss * (1.f / HDIM) + EPS) * w[lane];
  int pi = lane >> 1;
  float c = fcos[t * (HDIM/2) + pi], s = fsin[t * (HDIM/2) + pi];
  float other = __shfl_xor(vn, 1);
  float o = (lane & 1) ? (other * s + vn * c) : (vn * c - other * s);
  p[lane] = o;
}

// ---------------- causal flash attention, bf16 MFMA, GQA 4:1 ----------------
__global__ __launch_bounds__(256) void attn_mfma(const float* __restrict__ qb,
    const float* __restrict__ kb, const float* __restrict__ vb, float* __restrict__ ob) {
  int h = blockIdx.y;
  int qbase = blockIdx.x << 6;
  int kvh = h >> 2;
  int tid = threadIdx.x, wv = tid >> 6, lane = tid & 63;
  __shared__ short Kt[64][72];
  __shared__ short Vt[64][72];
  __shared__ short Pl[4][16][72];
  int arow = lane & 15;
  int akb = (lane >> 4) << 3;
  int kg = lane >> 4;
  int qrow_base = qbase + wv * 16;
  bf16x8 qf[2];
  {
    const float* qp = qb + (size_t)(qrow_base + arow) * (NHEADS*HDIM) + h * HDIM;
#pragma unroll
    for (int c = 0; c < 2; c++) {
      int d0 = akb + c * 32;
      union { bf16x8 v; unsigned u[4]; } r;
#pragma unroll
      for (int j = 0; j < 4; j++) r.u[j] = pk2bf(qp[d0 + 2*j], qp[d0 + 2*j + 1]);
      qf[c] = r.v;
    }
  }
  f32x4 accO[4];
  float m_[4], l_[4];
#pragma unroll
  for (int n = 0; n < 4; n++) { accO[n] = (f32x4){0.f,0.f,0.f,0.f}; m_[n] = -1e30f; l_[n] = 0.f; }
  int ntiles = (qbase >> 6) + 1;
  for (int ti = 0; ti < ntiles; ti++) {
    int ts = ti << 6;
#pragma unroll
    for (int i = 0; i < 16; i++) {
      int flat = tid + i * 256;
      int kk = flat >> 6, dd = flat & 63;
      size_t src = (size_t)(ts + kk) * (NKVH*HDIM) + kvh * HDIM + dd;
      Kt[kk][dd] = (short)rne1(kb[src]);
      Vt[dd][kk] = (short)rne1(vb[src]);
    }
    __syncthreads();
    f32x4 accS[4];
#pragma unroll
    for (int n = 0; n < 4; n++) accS[n] = (f32x4){0.f,0.f,0.f,0.f};
#pragma unroll
    for (int c = 0; c < 2; c++) {
#pragma unroll
      for (int n = 0; n < 4; n++) {
        bf16x8 bf = *(const bf16x8*)&Kt[n*16 + arow][c*32 + akb];
        accS[n] = mfma16(qf[c], bf, accS[n]);
      }
    }
#pragma unroll
    for (int ri = 0; ri < 4; ri++) {
      int qrow = qrow_base + kg*4 + ri;
      float mx = -1e30f;
#pragma unroll
      for (int n = 0; n < 4; n++) {
        int key = ts + n*16 + arow;
        float s = (key <= qrow) ? accS[n][ri] * 0.125f : -1e30f;
        accS[n][ri] = s;
        mx = fmaxf(mx, s);
      }
      for (int off = 1; off < 16; off <<= 1) mx = fmaxf(mx, __shfl_xor(mx, off));
      float mn = fmaxf(m_[ri], mx);
      float a = __expf(m_[ri] - mn);
      float sum = 0.f;
#pragma unroll
      for (int n = 0; n < 4; n++) {
        float p = __expf(accS[n][ri] - mn);
        accS[n][ri] = p;
        sum += p;
      }
      for (int off = 1; off < 16; off <<= 1) sum += __shfl_xor(sum, off);
      l_[ri] = l_[ri] * a + sum;
      m_[ri] = mn;
#pragma unroll
      for (int n = 0; n < 4; n++) accO[n][ri] *= a;
    }
#pragma unroll
    for (int ri = 0; ri < 4; ri++)
#pragma unroll
      for (int n = 0; n < 4; n++)
        Pl[wv][kg*4 + ri][n*16 + arow] = (short)rne1(accS[n][ri]);
#pragma unroll
    for (int c = 0; c < 2; c++) {
      bf16x8 pf = *(const bf16x8*)&Pl[wv][arow][c*32 + akb];
#pragma unroll
      for (int n = 0; n < 4; n++) {
        bf16x8 vf = *(const bf16x8*)&Vt[n*16 + arow][c*32 + akb];
        accO[n] = mfma16(pf, vf, accO[n]);
      }
    }
    __syncthreads();
  }
#pragma unroll
  for (int ri = 0; ri < 4; ri++) {
    int qrow = qrow_base + kg*4 + ri;
    float inv = 1.f / l_[ri];
#pragma unroll
    for (int n = 0; n < 4; n++)
      ob[(size_t)qrow * (NHEADS*HDIM) + h * HDIM + n*16 + arow] = accO[n][ri] * inv;
  }
}

// ---------------- gate: softmax -> top-6 (low-index tie-break) ----------------
__global__ __launch_bounds__(64) void gate_topk_k(const float* __restrict__ z,
    const float* __restrict__ gw, int* __restrict__ sel, float* __restrict__ topw,
    int* __restrict__ counts) {
  int t = blockIdx.x, lane = threadIdx.x;
  const float* zr = z + (size_t)t * D_MODEL;
  float acc = 0.f;
  for (int d = 0; d < D_MODEL; d += 4) {
    float4 zv = *(const float4*)(zr + d);
    acc += zv.x * gw[(size_t)(d + 0) * NEXP + lane];
    acc += zv.y * gw[(size_t)(d + 1) * NEXP + lane];
    acc += zv.z * gw[(size_t)(d + 2) * NEXP + lane];
    acc += zv.w * gw[(size_t)(d + 3) * NEXP + lane];
  }
  float m = acc;
  for (int off = 32; off; off >>= 1) m = fmaxf(m, __shfl_xor(m, off));
  float p = __expf(acc - m);
  float s = p;
  for (int off = 32; off; off >>= 1) s += __shfl_xor(s, off);
  p /= s;
  float rem = p, wsum = 0.f;
  float wvv[TOPK]; int wi[TOPK];
  for (int i = 0; i < TOPK; i++) {
    float v = rem; int idx = lane;
    for (int off = 32; off; off >>= 1) {
      float v2 = __shfl_xor(v, off);
      int i2 = __shfl_xor(idx, off);
      if (v2 > v || (v2 == v && i2 < idx)) { v = v2; idx = i2; }
    }
    wvv[i] = v; wi[i] = idx; wsum += v;
    if (lane == idx) rem = -1.f;
  }
  if (lane < TOPK) {
    sel[t * TOPK + lane] = wi[lane];
    topw[t * TOPK + lane] = wvv[lane] / wsum;
  }
  if (lane == 0)
    for (int i = 0; i < TOPK; i++) atomicAdd(&counts[wi[i]], 1);
}

// ---------------- scan + flattened (expert, mtile) work list (+shared tiles) -------
__global__ void scan_k(const int* __restrict__ counts, int* __restrict__ offs,
                       int* __restrict__ cursor, int* __restrict__ tile2e,
                       int* __restrict__ tile2mt, int* __restrict__ ntiles) {
  int lane = threadIdx.x;
  int c = counts[lane];
  int x = c;
  for (int off = 1; off < 64; off <<= 1) {
    int y = __shfl_up(x, off);
    if (lane >= off) x += y;
  }
  offs[lane] = x - c;
  cursor[lane] = x - c;
  int nt = (c + 127) >> 7;
  int y = nt;
  for (int off = 1; off < 64; off <<= 1) {
    int t2 = __shfl_up(y, off);
    if (lane >= off) y += t2;
  }
  int tbase = y - nt;
  for (int i = 0; i < nt; i++) { tile2e[tbase + i] = lane; tile2mt[tbase + i] = i; }
  if (lane == 63) {
    for (int i = 0; i < 8; i++) { tile2e[y + i] = NEXP; tile2mt[y + i] = i; }
    ntiles[0] = y + 8;
  }
}

__global__ void scatter_k(const int* __restrict__ sel, const float* __restrict__ topw,
    int* __restrict__ cursor, int* __restrict__ tok, float* __restrict__ wt) {
  int t = blockIdx.x * 256 + threadIdx.x;
  if (t >= SEQ) return;
  for (int i = 0; i < TOPK; i++) {
    int e = sel[t * TOPK + i];
    int pos = atomicAdd(&cursor[e], 1);
    tok[pos] = t;
    wt[pos] = topw[t * TOPK + i];
  }
}

// ---------------- MoE phase A: BN=64, relaxed barrier, TRUE depth-2 E/O pipeline ---
// grid = (HEXP/64 = 8, MAXTILES). K=1024, phase step 32, unroll x2.
__global__ __launch_bounds__(256) void moe_up8(const ushort* __restrict__ zb,
    const float* __restrict__ w1, const float* __restrict__ w3, size_t wstride,
    const float* __restrict__ sw1, const float* __restrict__ sw3,
    ushort* __restrict__ g, ushort* __restrict__ sg,
    const int* __restrict__ tok_list, const float* __restrict__ wt_list,
    const int* __restrict__ counts, const int* __restrict__ offs,
    const int* __restrict__ tile2e, const int* __restrict__ tile2mt,
    const int* __restrict__ ntiles) {
  int gt = blockIdx.y;
  if (gt >= ntiles[0]) return;
  int e = tile2e[gt];
  int mt = tile2mt[gt] << 7;
  bool sh = (e == NEXP);
  int cnt = sh ? SEQ : counts[e];
  int off = sh ? 0 : offs[e];
  const float* w1p = (sh ? sw1 : w1 + (size_t)e * wstride) + (blockIdx.x << 6);
  const float* w3p = (sh ? sw3 : w3 + (size_t)e * wstride) + (blockIdx.x << 6);
  ushort* gout = sh ? sg : g;
  __shared__ ushort Ah[2][128][40];
  __shared__ ushort Bs[2][2][32][74];
  __shared__ int toks[128];
  int tid = threadIdx.x, wv = tid >> 6, lane = tid & 63;
  int arow = lane & 15, akb = (lane >> 4) << 3, kg = lane >> 4;
  int c0l = wv * 16 + arow;
  int c0 = (blockIdx.x << 6) + c0l;
  if (tid < 128) {
    int r = mt + tid; if (r >= cnt) r = cnt - 1;
    toks[tid] = sh ? r : tok_list[off + r];
  }
  __syncthreads();
  int row0 = tid >> 2, q8 = (tid & 3) << 3, row1 = row0 + 64;
  const ushort* zr0 = zb + (size_t)toks[row0] * D_MODEL + q8;
  const ushort* zr1 = zb + (size_t)toks[row1] * D_MODEL + q8;
  int kB = tid >> 4, cB = (tid & 15) << 2;
  const float* w1q = w1p + (size_t)kB * HEXP + cB;
  const float* w3q = w3p + (size_t)kB * HEXP + cB;
  // prologue: E set = k0=0, O set = k0=32 (both in flight)
  uint4  raE0 = *(const uint4*)zr0;
  uint4  raE1 = *(const uint4*)zr1;
  float4 rbE1a = *(const float4*)w1q;
  float4 rbE1b = *(const float4*)(w1q + 16 * HEXP);
  float4 rbE3a = *(const float4*)w3q;
  float4 rbE3b = *(const float4*)(w3q + 16 * HEXP);
  uint4  raO0 = *(const uint4*)(zr0 + 32);
  uint4  raO1 = *(const uint4*)(zr1 + 32);
  float4 rbO1a = *(const float4*)(w1q + 32 * HEXP);
  float4 rbO1b = *(const float4*)(w1q + 48 * HEXP);
  float4 rbO3a = *(const float4*)(w3q + 32 * HEXP);
  float4 rbO3b = *(const float4*)(w3q + 48 * HEXP);
  f32x4 a1[8], a3[8];
#pragma unroll
  for (int f = 0; f < 8; f++) { a1[f] = (f32x4){0.f,0.f,0.f,0.f}; a3[f] = (f32x4){0.f,0.f,0.f,0.f}; }
  for (int k0 = 0; k0 < D_MODEL; k0 += 64) {
    { // even phase: data k0 (E set, buf0)
      *(uint4*)&Ah[0][row0][q8] = raE0;
      *(uint4*)&Ah[0][row1][q8] = raE1;
      unsigned* p1 = (unsigned*)&Bs[0][0][kB][cB];
      p1[0] = pk2bf(rbE1a.x, rbE1a.y); p1[1] = pk2bf(rbE1a.z, rbE1a.w);
      unsigned* p2 = (unsigned*)&Bs[0][0][kB + 16][cB];
      p2[0] = pk2bf(rbE1b.x, rbE1b.y); p2[1] = pk2bf(rbE1b.z, rbE1b.w);
      unsigned* p3 = (unsigned*)&Bs[0][1][kB][cB];
      p3[0] = pk2bf(rbE3a.x, rbE3a.y); p3[1] = pk2bf(rbE3a.z, rbE3a.w);
      unsigned* p4 = (unsigned*)&Bs[0][1][kB + 16][cB];
      p4[0] = pk2bf(rbE3b.x, rbE3b.y); p4[1] = pk2bf(rbE3b.z, rbE3b.w);
      barrier_nv();
      bf16x8 f1 = bfrag_lds<74>(&Bs[0][0][0][0], akb, c0l);
      bf16x8 f3 = bfrag_lds<74>(&Bs[0][1][0][0], akb, c0l);
#pragma unroll
      for (int f = 0; f < 8; f++) {
        bf16x8 ah = *(const bf16x8*)&Ah[0][f*16 + arow][akb];
        a1[f] = mfma16(ah, f1, a1[f]);
        a3[f] = mfma16(ah, f3, a3[f]);
      }
      int kp = k0 + 64; if (kp >= D_MODEL) kp = 0;
      raE0 = *(const uint4*)(zr0 + kp);
      raE1 = *(const uint4*)(zr1 + kp);
      rbE1a = *(const float4*)(w1q + (size_t)kp * HEXP);
      rbE1b = *(const float4*)(w1q + (size_t)(kp + 16) * HEXP);
      rbE3a = *(const float4*)(w3q + (size_t)kp * HEXP);
      rbE3b = *(const float4*)(w3q + (size_t)(kp + 16) * HEXP);
    }
    { // odd phase: data k0+32 (O set, buf1)
      *(uint4*)&Ah[1][row0][q8] = raO0;
      *(uint4*)&Ah[1][row1][q8] = raO1;
      unsigned* p1 = (unsigned*)&Bs[1][0][kB][cB];
      p1[0] = pk2bf(rbO1a.x, rbO1a.y); p1[1] = pk2bf(rbO1a.z, rbO1a.w);
      unsigned* p2 = (unsigned*)&Bs[1][0][kB + 16][cB];
      p2[0] = pk2bf(rbO1b.x, rbO1b.y); p2[1] = pk2bf(rbO1b.z, rbO1b.w);
      unsigned* p3 = (unsigned*)&Bs[1][1][kB][cB];
      p3[0] = pk2bf(rbO3a.x, rbO3a.y); p3[1] = pk2bf(rbO3a.z, rbO3a.w);
      unsigned* p4 = (unsigned*)&Bs[1][1][kB + 16][cB];
      p4[0] = pk2bf(rbO3b.x, rbO3b.y); p4[1] = pk2bf(rbO3b.z, rbO3b.w);
      barrier_nv();
      bf16x8 f1 = bfrag_lds<74>(&Bs[1][0][0][0], akb, c0l);
      bf16x8 f3 = bfrag_lds<74>(&Bs[1][1][0][0], akb, c0l);
#pragma unroll
      for (int f = 0; f < 8; f++) {
        bf16x8 ah = *(const bf16x8*)&Ah[1][f*16 + arow][akb];
        a1[f] = mfma16(ah, f1, a1[f]);
        a3[f] = mfma16(ah, f3, a3[f]);
      }
      int kp = k0 + 96; if (kp >= D_MODEL) kp = 0;
      raO0 = *(const uint4*)(zr0 + kp);
      raO1 = *(const uint4*)(zr1 + kp);
      rbO1a = *(const float4*)(w1q + (size_t)kp * HEXP);
      rbO1b = *(const float4*)(w1q + (size_t)(kp + 16) * HEXP);
      rbO3a = *(const float4*)(w3q + (size_t)kp * HEXP);
      rbO3b = *(const float4*)(w3q + (size_t)(kp + 16) * HEXP);
    }
  }
#pragma unroll
  for (int f = 0; f < 8; f++)
#pragma unroll
    for (int ri = 0; ri < 4; ri++) {
      int r = mt + f*16 + kg*4 + ri;
      if (r < cnt) {
        float wt = sh ? 1.0f : wt_list[off + r];
        float h1 = a1[f][ri], h3 = a3[f][ri];
        float gv = h1 / (1.f + __expf(-h1)) * h3 * wt;
        gout[(size_t)(off + r) * HEXP + c0] = (ushort)rne1(gv);
      }
    }
}

// ---------------- MoE phase B: BN=128, relaxed barrier, TRUE depth-2 E/O -----------
// grid = (D_MODEL/128 = 8, MAXTILES). K=512, phase step 32, unroll x2.
__global__ __launch_bounds__(256) void moe_down8(const ushort* __restrict__ g,
    const ushort* __restrict__ sg, const float* __restrict__ w2, size_t wstride,
    const float* __restrict__ sw2, float* __restrict__ out,
    const int* __restrict__ tok_list, const int* __restrict__ counts,
    const int* __restrict__ offs, const int* __restrict__ tile2e,
    const int* __restrict__ tile2mt, const int* __restrict__ ntiles) {
  int gt = blockIdx.y;
  if (gt >= ntiles[0]) return;
  int e = tile2e[gt];
  int mt = tile2mt[gt] << 7;
  bool sh = (e == NEXP);
  int cnt = sh ? SEQ : counts[e];
  int off = sh ? 0 : offs[e];
  const float* w2p = (sh ? sw2 : w2 + (size_t)e * wstride) + (blockIdx.x << 7);
  const ushort* gin = sh ? sg : g;
  __shared__ ushort Ah[2][128][40];
  __shared__ ushort Bs[2][32][138];
  int tid = threadIdx.x, wv = tid >> 6, lane = tid & 63;
  int arow = lane & 15, akb = (lane >> 4) << 3, kg = lane >> 4;
  int c0l = wv * 32 + arow;
  int c0 = (blockIdx.x << 7) + c0l;
  int row0 = tid >> 2, q8 = (tid & 3) << 3, row1 = row0 + 64;
  int rr0 = mt + row0; if (rr0 >= cnt) rr0 = cnt - 1;
  int rr1 = mt + row1; if (rr1 >= cnt) rr1 = cnt - 1;
  const ushort* gr0 = gin + (size_t)(off + rr0) * HEXP + q8;
  const ushort* gr1 = gin + (size_t)(off + rr1) * HEXP + q8;
  int kB = tid >> 3, cB = (tid & 7) << 4;
  const float* w2q = w2p + (size_t)kB * D_MODEL + cB;
  // prologue: E = k0=0, O = k0=32
  uint4  raE0 = *(const uint4*)gr0;
  uint4  raE1 = *(const uint4*)gr1;
  float4 rbE0 = *(const float4*)(w2q);
  float4 rbE1 = *(const float4*)(w2q + 4);
  float4 rbE2 = *(const float4*)(w2q + 8);
  float4 rbE3 = *(const float4*)(w2q + 12);
  uint4  raO0 = *(const uint4*)(gr0 + 32);
  uint4  raO1 = *(const uint4*)(gr1 + 32);
  const float* w2o = w2q + (size_t)32 * D_MODEL;
  float4 rbO0 = *(const float4*)(w2o);
  float4 rbO1 = *(const float4*)(w2o + 4);
  float4 rbO2 = *(const float4*)(w2o + 8);
  float4 rbO3 = *(const float4*)(w2o + 12);
  f32x4 ac0[8], ac1[8];
#pragma unroll
  for (int f = 0; f < 8; f++) { ac0[f] = (f32x4){0.f,0.f,0.f,0.f}; ac1[f] = (f32x4){0.f,0.f,0.f,0.f}; }
  for (int k0 = 0; k0 < HEXP; k0 += 64) {
    { // even phase: data k0 (E, buf0)
      *(uint4*)&Ah[0][row0][q8] = raE0;
      *(uint4*)&Ah[0][row1][q8] = raE1;
      unsigned* p = (unsigned*)&Bs[0][kB][cB];
      p[0] = pk2bf(rbE0.x, rbE0.y); p[1] = pk2bf(rbE0.z, rbE0.w);
      p[2] = pk2bf(rbE1.x, rbE1.y); p[3] = pk2bf(rbE1.z, rbE1.w);
      p[4] = pk2bf(rbE2.x, rbE2.y); p[5] = pk2bf(rbE2.z, rbE2.w);
      p[6] = pk2bf(rbE3.x, rbE3.y); p[7] = pk2bf(rbE3.z, rbE3.w);
      barrier_nv();
      bf16x8 f0 = bfrag_lds<138>(&Bs[0][0][0], akb, c0l);
      bf16x8 f1 = bfrag_lds<138>(&Bs[0][0][0], akb, c0l + 16);
#pragma unroll
      for (int f = 0; f < 8; f++) {
        bf16x8 ah = *(const bf16x8*)&Ah[0][f*16 + arow][akb];
        ac0[f] = mfma16(ah, f0, ac0[f]);
        ac1[f] = mfma16(ah, f1, ac1[f]);
      }
      int kp = k0 + 64; if (kp >= HEXP) kp = 0;
      raE0 = *(const uint4*)(gr0 + kp);
      raE1 = *(const uint4*)(gr1 + kp);
      const float* wn = w2q + (size_t)kp * D_MODEL;
      rbE0 = *(const float4*)(wn);
      rbE1 = *(const float4*)(wn + 4);
      rbE2 = *(const float4*)(wn + 8);
      rbE3 = *(const float4*)(wn + 12);
    }
    { // odd phase: data k0+32 (O, buf1)
      *(uint4*)&Ah[1][row0][q8] = raO0;
      *(uint4*)&Ah[1][row1][q8] = raO1;
      unsigned* p = (unsigned*)&Bs[1][kB][cB];
      p[0] = pk2bf(rbO0.x, rbO0.y); p[1] = pk2bf(rbO0.z, rbO0.w);
      p[2] = pk2bf(rbO1.x, rbO1.y); p[3] = pk2bf(rbO1.z, rbO1.w);
      p[4] = pk2bf(rbO2.x, rbO2.y); p[5] = pk2bf(rbO2.z, rbO2.w);
      p[6] = pk2bf(rbO3.x, rbO3.y); p[7] = pk2bf(rbO3.z, rbO3.w);
      barrier_nv();
      bf16x8 f0 = bfrag_lds<138>(&Bs[1][0][0], akb, c0l);
      bf16x8 f1 = bfrag_lds<138>(&Bs[1][0][0], akb, c0l + 16);
#pragma unroll
      for (int f = 0; f < 8; f++) {
        bf16x8 ah = *(const bf16x8*)&Ah[1][f*16 + arow][akb];
        ac0[f] = mfma16(ah, f0, ac0[f]);
        ac1[f] = mfma16(ah, f1, ac1[f]);
      }
      int kp = k0 + 96; if (kp >= HEXP) kp = 0;
      raO0 = *(const uint4*)(gr0 + kp);
      raO1 = *(const uint4*)(gr1 + kp);
      const float* wn = w2q + (size_t)kp * D_MODEL;
      rbO0 = *(const float4*)(wn);
      rbO1 = *(const float4*)(wn + 4);
      rbO2 = *(const float4*)(wn + 8);
      rbO3 = *(const float4*)(wn + 12);
    }
  }
#pragma unroll
  for (int f = 0; f < 8; f++)
#pragma unroll
    for (int ri = 0; ri < 4; ri++) {
      int r = mt + f*16 + kg*4 + ri;
      if (r < cnt) {
        int tok = sh ? r : tok_list[off + r];
        float* op = out + (size_t)tok * D_MODEL + c0;
        atomicAdd(op, ac0[f][ri]);
        atomicAdd(op + 16, ac1[f][ri]);
      }
    }
}

// ---------------- host ----------------
extern "C" void kernel_launch(void* const* d_in, const int* in_sizes, int n_in,
                              void* d_out, int out_size, void* d_ws, size_t ws_size,
                              hipStream_t stream) {
  const float* x     = (const float*)d_in[0];
  const float* fcos  = (const float*)d_in[1];
  const float* fsin  = (const float*)d_in[2];
  const float* anw   = (const float*)d_in[3];
  const float* fnw   = (const float*)d_in[4];
  const float* wq    = (const float*)d_in[5];
  const float* wk    = (const float*)d_in[6];
  const float* wvv   = (const float*)d_in[7];
  const float* wo    = (const float*)d_in[8];
  const float* qnw   = (const float*)d_in[9];
  const float* knw   = (const float*)d_in[10];
  const float* gatew = (const float*)d_in[11];
  const float* w1e   = (const float*)d_in[12];
  const float* w3e   = (const float*)d_in[13];
  const float* w2e   = (const float*)d_in[14];
  const float* sw1   = (const float*)d_in[15];
  const float* sw3   = (const float*)d_in[16];
  const float* sw2   = (const float*)d_in[17];
  float* out = (float*)d_out;

  char* ws = (char*)d_ws;
  const size_t MB = 1ull << 20;
  float*  hx    = (float*)(ws);             // 4MB (attn-norm out, then attn out)
  float*  h     = (float*)(ws + 4*MB);      // 4MB residual after attention
  float*  z     = (float*)(ws + 8*MB);      // 4MB ffn-norm out (f32, for gate)
  float*  qbuf  = (float*)(ws + 12*MB);     // 4MB   (dead after attention)
  float*  kbuf  = (float*)(ws + 16*MB);     // 1MB
  float*  vbuf  = (float*)(ws + 17*MB);     // 1MB
  ushort* zb    = (ushort*)(ws + 12*MB);    // 2MB bf16 z (overlaps dead qbuf)
  ushort* gb    = (ushort*)(ws + 14*MB);    // 6.3MB bf16 expert activations
  ushort* s_gb  = (ushort*)(ws + 20*MB + 512*1024); // 1MB shared-expert act
  char*   misc  = ws + 22*MB;
  int*   sel      = (int*)(misc);
  float* topw     = (float*)(misc + 24576);
  int*   counts   = (int*)(misc + 49152);
  int*   offs     = (int*)(misc + 49408);
  int*   cursor   = (int*)(misc + 49664);
  int*   ntiles   = (int*)(misc + 50432);
  int*   tile2e   = (int*)(misc + 50688);
  int*   tile2mt  = (int*)(misc + 51200);
  int*   tok_list = (int*)(misc + 51712);
  float* wt_list  = (float*)(misc + 76288);

  // 1. attn rmsnorm
  rmsnorm_k<<<SEQ, 256, 0, stream>>>(x, anw, hx, nullptr);
  // 2. QKV projections (split-bf16 MFMA, relaxed-barrier pipeline)
  mfma_gemm_k<<<dim3(8, 64), 256, 0, stream>>>(hx, wq, qbuf, nullptr, nullptr, 1024, 1024);
  mfma_gemm_k<<<dim3(2, 64), 256, 0, stream>>>(hx, wk, kbuf, nullptr, nullptr, 256, 1024);
  mfma_gemm_k<<<dim3(2, 64), 256, 0, stream>>>(hx, wvv, vbuf, nullptr, nullptr, 256, 1024);
  // 3. q/k rmsnorm + rope
  qknorm_rope_k<<<dim3(SEQ, NHEADS + NKVH), 64, 0, stream>>>(qbuf, kbuf, qnw, knw, fcos, fsin);
  // 4. causal flash attention (bf16 MFMA) -> hx
  attn_mfma<<<dim3(SEQ / 64, NHEADS), 256, 0, stream>>>(qbuf, kbuf, vbuf, hx);
  // 5. o @ wo + x -> h (and d_out = h)
  mfma_gemm_k<<<dim3(8, 64), 256, 0, stream>>>(hx, wo, h, out, x, 1024, 1024);
  // 6. ffn rmsnorm -> z (f32) + zb (bf16)
  rmsnorm_k<<<SEQ, 256, 0, stream>>>(h, fnw, z, zb);
  // 7. gate + top-k + bucketing + flattened tile list (incl. shared tiles)
  hipMemsetAsync(counts, 0, 256, stream);
  gate_topk_k<<<SEQ, 64, 0, stream>>>(z, gatew, sel, topw, counts);
  scan_k<<<1, 64, 0, stream>>>(counts, offs, cursor, tile2e, tile2mt, ntiles);
  scatter_k<<<SEQ / 256, 256, 0, stream>>>(sel, topw, cursor, tok_list, wt_list);
  // 8. MoE phase A (experts + shared expert in one dispatch)
  moe_up8<<<dim3(HEXP / 64, MAXTILES), 256, 0, stream>>>(zb, w1e, w3e,
      (size_t)D_MODEL * HEXP, sw1, sw3, gb, s_gb, tok_list, wt_list,
      counts, offs, tile2e, tile2mt, ntiles);
  // 9. MoE phase B (experts + shared expert in one dispatch)
  moe_down8<<<dim3(D_MODEL / 128, MAXTILES), 256, 0, stream>>>(gb, s_gb, w2e,
      (size_t)HEXP * D_MODEL, sw2, out, tok_list, counts, offs,
      tile2e, tile2mt, ntiles);
  (void)in_sizes; (void)n_in; (void)out_size; (void)ws_size;
}

// Round 11
// 414.032 us; speedup vs baseline: 1.0924x; 1.0924x over previous
//
#include <hip/hip_runtime.h>
#include <hip/hip_bf16.h>
#include <math.h>

#define D_MODEL 1024
#define SEQ     1024
#define NHEADS  16
#define NKVH    4
#define HDIM    64
#define NEXP    64
#define TOPK    6
#define HEXP    512
#define EPS     1e-5f
#define MAXTILES 120   // 112 expert tiles max + 8 shared-expert tiles

typedef __attribute__((ext_vector_type(8))) short bf16x8;
typedef __attribute__((ext_vector_type(4))) float f32x4;

struct bfrag2 { bf16x8 hi, lo; };
struct f32x8r { float v[8]; };

__device__ __forceinline__ unsigned rne1(float a) {
  union { float f; unsigned u; } x; x.f = a;
  return (x.u + 0x7fffu + ((x.u >> 16) & 1u)) >> 16;
}
__device__ __forceinline__ float frombf(unsigned h) {
  union { float f; unsigned u; } x; x.u = h << 16; return x.f;
}
__device__ __forceinline__ void split_pack(float a, float b, unsigned& hi, unsigned& lo) {
  unsigned ha = rne1(a), hb = rne1(b);
  hi = ha | (hb << 16);
  lo = rne1(a - frombf(ha)) | (rne1(b - frombf(hb)) << 16);
}
__device__ __forceinline__ unsigned pk2bf(float a, float b) {
  return rne1(a) | (rne1(b) << 16);
}

__device__ __forceinline__ f32x4 mfma16(bf16x8 a, bf16x8 b, f32x4 c) {
  return __builtin_amdgcn_mfma_f32_16x16x32_bf16(a, b, c, 0, 0, 0);
}
__device__ __forceinline__ f32x4 mfma_sp(bf16x8 ah, bf16x8 al, const bfrag2& b, f32x4 c) {
  c = mfma16(ah, b.hi, c);
  c = mfma16(ah, b.lo, c);
  c = mfma16(al, b.hi, c);
  return c;
}

// barrier WITHOUT the compiler's vmcnt(0) drain
__device__ __forceinline__ void barrier_nv() {
  asm volatile("s_waitcnt lgkmcnt(0)" ::: "memory");
  __builtin_amdgcn_s_barrier();
}

// async global->LDS DMA, 16 bytes per lane, dest = uniform base + lane*16
__device__ __forceinline__ void gload16(const void* g, void* l) {
  __builtin_amdgcn_global_load_lds(
      (const __attribute__((address_space(1))) void*)g,
      (__attribute__((address_space(3))) void*)l, 16, 0, 0);
}

__device__ __forceinline__ f32x8r loadraw8(const float* __restrict__ p, int ld) {
  f32x8r r;
#pragma unroll
  for (int i = 0; i < 8; i++) r.v[i] = p[(size_t)ld * i];
  return r;
}
__device__ __forceinline__ bfrag2 cvt_bf2(const f32x8r& f) {
  union { bf16x8 v; unsigned u[4]; } H, L;
  split_pack(f.v[0], f.v[1], H.u[0], L.u[0]);
  split_pack(f.v[2], f.v[3], H.u[1], L.u[1]);
  split_pack(f.v[4], f.v[5], H.u[2], L.u[2]);
  split_pack(f.v[6], f.v[7], H.u[3], L.u[3]);
  bfrag2 r; r.hi = H.v; r.lo = L.v; return r;
}
__device__ __forceinline__ bf16x8 pack8(const float* v) {
  union { bf16x8 b; unsigned u[4]; } r;
  r.u[0] = pk2bf(v[0], v[1]); r.u[1] = pk2bf(v[2], v[3]);
  r.u[2] = pk2bf(v[4], v[5]); r.u[3] = pk2bf(v[6], v[7]);
  return r.b;
}

// ---------------- rmsnorm over D=1024 (+ optional bf16 copy) ----------------
__global__ __launch_bounds__(256) void rmsnorm_k(const float* __restrict__ x,
    const float* __restrict__ w, float* __restrict__ out, ushort* __restrict__ outb) {
  int t = blockIdx.x;
  const float4* xr = (const float4*)(x + (size_t)t * D_MODEL);
  float4 v = xr[threadIdx.x];
  float ss = v.x*v.x + v.y*v.y + v.z*v.z + v.w*v.w;
  for (int off = 32; off; off >>= 1) ss += __shfl_xor(ss, off);
  __shared__ float red[4];
  if ((threadIdx.x & 63) == 0) red[threadIdx.x >> 6] = ss;
  __syncthreads();
  float tot = red[0] + red[1] + red[2] + red[3];
  float inv = rsqrtf(tot * (1.f / D_MODEL) + EPS);
  float4 wv = ((const float4*)w)[threadIdx.x];
  float4 o;
  o.x = v.x * inv * wv.x; o.y = v.y * inv * wv.y;
  o.z = v.z * inv * wv.z; o.w = v.w * inv * wv.w;
  ((float4*)(out + (size_t)t * D_MODEL))[threadIdx.x] = o;
  if (outb) {
    uint2 b;
    b.x = pk2bf(o.x, o.y); b.y = pk2bf(o.z, o.w);
    *(uint2*)(outb + (size_t)t * D_MODEL + threadIdx.x * 4) = b;
  }
}

// ---------------- dense split-bf16 MFMA GEMM, depth-2 pipeline, relaxed barrier ----
__global__ __launch_bounds__(256) void mfma_gemm_k(const float* __restrict__ A,
    const float* __restrict__ B, float* __restrict__ C, float* __restrict__ C2,
    const float* __restrict__ resid, int N, int K) {
  __shared__ short Ah[2][16][40];
  __shared__ short Al[2][16][40];
  int bm = blockIdx.y << 4, bn = blockIdx.x << 7;
  int tid = threadIdx.x, wv = tid >> 6, lane = tid & 63;
  int m_ = tid >> 4, k_ = (tid & 15) << 1;
  int arow = lane & 15, akb = (lane >> 4) << 3;
  int c0 = bn + wv * 32 + arow;
  const float* ar = A + (size_t)(bm + m_) * K + k_;
  {
    float2 a0 = *(const float2*)ar;
    unsigned hi, lo; split_pack(a0.x, a0.y, hi, lo);
    *(unsigned*)&Ah[0][m_][k_] = hi;
    *(unsigned*)&Al[0][m_][k_] = lo;
  }
  float2 aO = *(const float2*)(ar + 32);
  float2 aE;
  f32x8r bE0 = loadraw8(B + (size_t)akb * N + c0, N);
  f32x8r bE1 = loadraw8(B + (size_t)akb * N + c0 + 16, N);
  f32x8r bO0 = loadraw8(B + (size_t)(32 + akb) * N + c0, N);
  f32x8r bO1 = loadraw8(B + (size_t)(32 + akb) * N + c0 + 16, N);
  __syncthreads();
  f32x4 acc0 = {0.f,0.f,0.f,0.f}, acc1 = {0.f,0.f,0.f,0.f};
  for (int k0 = 0; k0 < K; k0 += 64) {
    { // even
      int kp = (k0 + 64 < K) ? k0 + 64 : 0;
      f32x8r n0 = loadraw8(B + (size_t)(kp + akb) * N + c0, N);
      f32x8r n1 = loadraw8(B + (size_t)(kp + akb) * N + c0 + 16, N);
      float2 an = *(const float2*)(ar + kp);
      bfrag2 f0 = cvt_bf2(bE0), f1 = cvt_bf2(bE1);
      bf16x8 ah = *(const bf16x8*)&Ah[0][arow][akb];
      bf16x8 al = *(const bf16x8*)&Al[0][arow][akb];
      acc0 = mfma_sp(ah, al, f0, acc0);
      acc1 = mfma_sp(ah, al, f1, acc1);
      unsigned hi, lo; split_pack(aO.x, aO.y, hi, lo);
      *(unsigned*)&Ah[1][m_][k_] = hi;
      *(unsigned*)&Al[1][m_][k_] = lo;
      barrier_nv();
      bE0 = n0; bE1 = n1; aE = an;
    }
    { // odd
      int kp = (k0 + 96 < K) ? k0 + 96 : 0;
      f32x8r n0 = loadraw8(B + (size_t)(kp + akb) * N + c0, N);
      f32x8r n1 = loadraw8(B + (size_t)(kp + akb) * N + c0 + 16, N);
      float2 an = *(const float2*)(ar + kp);
      bfrag2 f0 = cvt_bf2(bO0), f1 = cvt_bf2(bO1);
      bf16x8 ah = *(const bf16x8*)&Ah[1][arow][akb];
      bf16x8 al = *(const bf16x8*)&Al[1][arow][akb];
      acc0 = mfma_sp(ah, al, f0, acc0);
      acc1 = mfma_sp(ah, al, f1, acc1);
      unsigned hi, lo; split_pack(aE.x, aE.y, hi, lo);
      *(unsigned*)&Ah[0][m_][k_] = hi;
      *(unsigned*)&Al[0][m_][k_] = lo;
      barrier_nv();
      bO0 = n0; bO1 = n1; aO = an;
    }
  }
  int r0 = (lane >> 4) << 2;
#pragma unroll
  for (int ri = 0; ri < 4; ri++) {
    int row = bm + r0 + ri;
    size_t o0 = (size_t)row * N + c0;
    float v0 = acc0[ri], v1 = acc1[ri];
    if (resid) { v0 += resid[o0]; v1 += resid[o0 + 16]; }
    C[o0] = v0; C[o0 + 16] = v1;
    if (C2) { C2[o0] = v0; C2[o0 + 16] = v1; }
  }
}

// ---------------- per-head rmsnorm + RoPE ----------------
__global__ __launch_bounds__(64) void qknorm_rope_k(float* __restrict__ qb,
    float* __restrict__ kb, const float* __restrict__ qw, const float* __restrict__ kw,
    const float* __restrict__ fcos, const float* __restrict__ fsin) {
  int t = blockIdx.x, hid = blockIdx.y, lane = threadIdx.x;
  float* p; const float* w;
  if (hid < NHEADS) { p = qb + (size_t)t * (NHEADS*HDIM) + hid * HDIM; w = qw; }
  else              { p = kb + (size_t)t * (NKVH*HDIM) + (hid - NHEADS) * HDIM; w = kw; }
  float v = p[lane];
  float ss = v * v;
  for (int off = 32; off; off >>= 1) ss += __shfl_xor(ss, off);
  float vn = v * rsqrtf(ss * (1.f / HDIM) + EPS) * w[lane];
  int pi = lane >> 1;
  float c = fcos[t * (HDIM/2) + pi], s = fsin[t * (HDIM/2) + pi];
  float other = __shfl_xor(vn, 1);
  float o = (lane & 1) ? (other * s + vn * c) : (vn * c - other * s);
  p[lane] = o;
}

// ---------------- causal flash attention, bf16 MFMA, GQA 4:1 ----------------
__global__ __launch_bounds__(256) void attn_mfma(const float* __restrict__ qb,
    const float* __restrict__ kb, const float* __restrict__ vb, float* __restrict__ ob) {
  int h = blockIdx.y;
  int qbase = blockIdx.x << 6;
  int kvh = h >> 2;
  int tid = threadIdx.x, wv = tid >> 6, lane = tid & 63;
  __shared__ short Kt[64][72];
  __shared__ short Vt[64][72];
  __shared__ short Pl[4][16][72];
  int arow = lane & 15;
  int akb = (lane >> 4) << 3;
  int kg = lane >> 4;
  int qrow_base = qbase + wv * 16;
  bf16x8 qf[2];
  {
    const float* qp = qb + (size_t)(qrow_base + arow) * (NHEADS*HDIM) + h * HDIM;
#pragma unroll
    for (int c = 0; c < 2; c++) {
      int d0 = akb + c * 32;
      union { bf16x8 v; unsigned u[4]; } r;
#pragma unroll
      for (int j = 0; j < 4; j++) r.u[j] = pk2bf(qp[d0 + 2*j], qp[d0 + 2*j + 1]);
      qf[c] = r.v;
    }
  }
  f32x4 accO[4];
  float m_[4], l_[4];
#pragma unroll
  for (int n = 0; n < 4; n++) { accO[n] = (f32x4){0.f,0.f,0.f,0.f}; m_[n] = -1e30f; l_[n] = 0.f; }
  int ntiles = (qbase >> 6) + 1;
  for (int ti = 0; ti < ntiles; ti++) {
    int ts = ti << 6;
#pragma unroll
    for (int i = 0; i < 16; i++) {
      int flat = tid + i * 256;
      int kk = flat >> 6, dd = flat & 63;
      size_t src = (size_t)(ts + kk) * (NKVH*HDIM) + kvh * HDIM + dd;
      Kt[kk][dd] = (short)rne1(kb[src]);
      Vt[dd][kk] = (short)rne1(vb[src]);
    }
    __syncthreads();
    f32x4 accS[4];
#pragma unroll
    for (int n = 0; n < 4; n++) accS[n] = (f32x4){0.f,0.f,0.f,0.f};
#pragma unroll
    for (int c = 0; c < 2; c++) {
#pragma unroll
      for (int n = 0; n < 4; n++) {
        bf16x8 bf = *(const bf16x8*)&Kt[n*16 + arow][c*32 + akb];
        accS[n] = mfma16(qf[c], bf, accS[n]);
      }
    }
#pragma unroll
    for (int ri = 0; ri < 4; ri++) {
      int qrow = qrow_base + kg*4 + ri;
      float mx = -1e30f;
#pragma unroll
      for (int n = 0; n < 4; n++) {
        int key = ts + n*16 + arow;
        float s = (key <= qrow) ? accS[n][ri] * 0.125f : -1e30f;
        accS[n][ri] = s;
        mx = fmaxf(mx, s);
      }
      for (int off = 1; off < 16; off <<= 1) mx = fmaxf(mx, __shfl_xor(mx, off));
      float mn = fmaxf(m_[ri], mx);
      float a = __expf(m_[ri] - mn);
      float sum = 0.f;
#pragma unroll
      for (int n = 0; n < 4; n++) {
        float p = __expf(accS[n][ri] - mn);
        accS[n][ri] = p;
        sum += p;
      }
      for (int off = 1; off < 16; off <<= 1) sum += __shfl_xor(sum, off);
      l_[ri] = l_[ri] * a + sum;
      m_[ri] = mn;
#pragma unroll
      for (int n = 0; n < 4; n++) accO[n][ri] *= a;
    }
#pragma unroll
    for (int ri = 0; ri < 4; ri++)
#pragma unroll
      for (int n = 0; n < 4; n++)
        Pl[wv][kg*4 + ri][n*16 + arow] = (short)rne1(accS[n][ri]);
#pragma unroll
    for (int c = 0; c < 2; c++) {
      bf16x8 pf = *(const bf16x8*)&Pl[wv][arow][c*32 + akb];
#pragma unroll
      for (int n = 0; n < 4; n++) {
        bf16x8 vf = *(const bf16x8*)&Vt[n*16 + arow][c*32 + akb];
        accO[n] = mfma16(pf, vf, accO[n]);
      }
    }
    __syncthreads();
  }
#pragma unroll
  for (int ri = 0; ri < 4; ri++) {
    int qrow = qrow_base + kg*4 + ri;
    float inv = 1.f / l_[ri];
#pragma unroll
    for (int n = 0; n < 4; n++)
      ob[(size_t)qrow * (NHEADS*HDIM) + h * HDIM + n*16 + arow] = accO[n][ri] * inv;
  }
}

// ---------------- gate: softmax -> top-6 (low-index tie-break) ----------------
__global__ __launch_bounds__(64) void gate_topk_k(const float* __restrict__ z,
    const float* __restrict__ gw, int* __restrict__ sel, float* __restrict__ topw,
    int* __restrict__ counts) {
  int t = blockIdx.x, lane = threadIdx.x;
  const float* zr = z + (size_t)t * D_MODEL;
  float acc = 0.f;
  for (int d = 0; d < D_MODEL; d += 4) {
    float4 zv = *(const float4*)(zr + d);
    acc += zv.x * gw[(size_t)(d + 0) * NEXP + lane];
    acc += zv.y * gw[(size_t)(d + 1) * NEXP + lane];
    acc += zv.z * gw[(size_t)(d + 2) * NEXP + lane];
    acc += zv.w * gw[(size_t)(d + 3) * NEXP + lane];
  }
  float m = acc;
  for (int off = 32; off; off >>= 1) m = fmaxf(m, __shfl_xor(m, off));
  float p = __expf(acc - m);
  float s = p;
  for (int off = 32; off; off >>= 1) s += __shfl_xor(s, off);
  p /= s;
  float rem = p, wsum = 0.f;
  float wvv[TOPK]; int wi[TOPK];
  for (int i = 0; i < TOPK; i++) {
    float v = rem; int idx = lane;
    for (int off = 32; off; off >>= 1) {
      float v2 = __shfl_xor(v, off);
      int i2 = __shfl_xor(idx, off);
      if (v2 > v || (v2 == v && i2 < idx)) { v = v2; idx = i2; }
    }
    wvv[i] = v; wi[i] = idx; wsum += v;
    if (lane == idx) rem = -1.f;
  }
  if (lane < TOPK) {
    sel[t * TOPK + lane] = wi[lane];
    topw[t * TOPK + lane] = wvv[lane] / wsum;
  }
  if (lane == 0)
    for (int i = 0; i < TOPK; i++) atomicAdd(&counts[wi[i]], 1);
}

// ---------------- scan + flattened (expert, mtile) work list (+shared tiles) -------
__global__ void scan_k(const int* __restrict__ counts, int* __restrict__ offs,
                       int* __restrict__ cursor, int* __restrict__ tile2e,
                       int* __restrict__ tile2mt, int* __restrict__ ntiles) {
  int lane = threadIdx.x;
  int c = counts[lane];
  int x = c;
  for (int off = 1; off < 64; off <<= 1) {
    int y = __shfl_up(x, off);
    if (lane >= off) x += y;
  }
  offs[lane] = x - c;
  cursor[lane] = x - c;
  int nt = (c + 127) >> 7;
  int y = nt;
  for (int off = 1; off < 64; off <<= 1) {
    int t2 = __shfl_up(y, off);
    if (lane >= off) y += t2;
  }
  int tbase = y - nt;
  for (int i = 0; i < nt; i++) { tile2e[tbase + i] = lane; tile2mt[tbase + i] = i; }
  if (lane == 63) {
    for (int i = 0; i < 8; i++) { tile2e[y + i] = NEXP; tile2mt[y + i] = i; }
    ntiles[0] = y + 8;
  }
}

__global__ void scatter_k(const int* __restrict__ sel, const float* __restrict__ topw,
    int* __restrict__ cursor, int* __restrict__ tok, float* __restrict__ wt) {
  int t = blockIdx.x * 256 + threadIdx.x;
  if (t >= SEQ) return;
  for (int i = 0; i < TOPK; i++) {
    int e = sel[t * TOPK + i];
    int pos = atomicAdd(&cursor[e], 1);
    tok[pos] = t;
    wt[pos] = topw[t * TOPK + i];
  }
}

// ---------------- MoE phase A: pure-DMA staging, 3-buf counted-vmcnt pipeline ------
// grid = (HEXP/64 = 8, MAXTILES). K=1024, step 32, NT=32.
__global__ __launch_bounds__(256) void moe_up9(const ushort* __restrict__ zb,
    const float* __restrict__ w1, const float* __restrict__ w3, size_t wstride,
    const float* __restrict__ sw1, const float* __restrict__ sw3,
    ushort* __restrict__ g, ushort* __restrict__ sg,
    const int* __restrict__ tok_list, const float* __restrict__ wt_list,
    const int* __restrict__ counts, const int* __restrict__ offs,
    const int* __restrict__ tile2e, const int* __restrict__ tile2mt,
    const int* __restrict__ ntiles) {
  int gt = blockIdx.y;
  if (gt >= ntiles[0]) return;
  int e = tile2e[gt];
  int mt = tile2mt[gt] << 7;
  bool sh = (e == NEXP);
  int cnt = sh ? SEQ : counts[e];
  int off = sh ? 0 : offs[e];
  const float* w1p = (sh ? sw1 : w1 + (size_t)e * wstride) + (blockIdx.x << 6);
  const float* w3p = (sh ? sw3 : w3 + (size_t)e * wstride) + (blockIdx.x << 6);
  ushort* gout = sh ? sg : g;
  // LDS: A chunk-major [buf][chunk(8k)][row][8 ushort]; B row-major f32, src-swizzled
  __shared__ __align__(16) ushort A_s[3][4][128][8];
  __shared__ __align__(16) float  B1_s[3][32][64];
  __shared__ __align__(16) float  B3_s[3][32][64];
  int tid = threadIdx.x, wv = tid >> 6, lane = tid & 63;
  int arow = lane & 15, kg = lane >> 4, akb = kg << 3;
  int c0l = wv * 16 + arow;
  int c0 = (blockIdx.x << 6) + c0l;
  // per-lane token rows (rows lane and 64+lane of the tile)
  int r0i = mt + lane;        if (r0i >= cnt) r0i = cnt - 1;
  int r1i = mt + 64 + lane;   if (r1i >= cnt) r1i = cnt - 1;
  int tok0 = sh ? r0i : tok_list[off + r0i];
  int tok1 = sh ? r1i : tok_list[off + r1i];
  const ushort* aS0 = zb + (size_t)tok0 * D_MODEL + wv * 8;
  const ushort* aS1 = zb + (size_t)tok1 * D_MODEL + wv * 8;
  // B DMA per-lane source: rows 8wv + p*4 + lane/16, col-chunk (lane&15)^wv (16B units)
  const float* b1l = w1p + (size_t)(8 * wv + (lane >> 4)) * HEXP + (((lane & 15) ^ wv) << 2);
  const float* b3l = w3p + (size_t)(8 * wv + (lane >> 4)) * HEXP + (((lane & 15) ^ wv) << 2);
  const int NT = D_MODEL / 32;
  auto STAGE = [&](int b, int sidx) {
    int kk = (sidx < NT ? sidx : sidx - NT) * 32;
    gload16(aS0 + kk, &A_s[b][wv][0][0]);
    gload16(aS1 + kk, &A_s[b][wv][64][0]);
    gload16(b1l + (size_t)kk * HEXP, &B1_s[b][8 * wv][0]);
    gload16(b1l + (size_t)(kk + 4) * HEXP, &B1_s[b][8 * wv + 4][0]);
    gload16(b3l + (size_t)kk * HEXP, &B3_s[b][8 * wv][0]);
    gload16(b3l + (size_t)(kk + 4) * HEXP, &B3_s[b][8 * wv + 4][0]);
  };
  STAGE(0, 0); STAGE(1, 1); STAGE(2, 2);
  int cs = ((((c0l >> 2) ^ kg) << 2) | (c0l & 3));  // swizzled col for B reads
  f32x4 a1[8], a3[8];
#pragma unroll
  for (int f = 0; f < 8; f++) { a1[f] = (f32x4){0.f,0.f,0.f,0.f}; a3[f] = (f32x4){0.f,0.f,0.f,0.f}; }
  for (int s = 0; s < NT; ++s) {
    int b = s % 3;
    asm volatile("s_waitcnt vmcnt(12)" ::: "memory");
    __builtin_amdgcn_s_barrier();
    bf16x8 af[8];
#pragma unroll
    for (int f = 0; f < 8; f++) af[f] = *(const bf16x8*)&A_s[b][kg][f*16 + arow][0];
    float v1[8], v3[8];
#pragma unroll
    for (int j = 0; j < 8; j++) v1[j] = B1_s[b][akb + j][cs];
#pragma unroll
    for (int j = 0; j < 8; j++) v3[j] = B3_s[b][akb + j][cs];
    asm volatile("s_waitcnt lgkmcnt(0)" ::: "memory");
    __builtin_amdgcn_s_barrier();
    STAGE(b, s + 3);
    bf16x8 f1 = pack8(v1), f3 = pack8(v3);
#pragma unroll
    for (int f = 0; f < 8; f++) {
      a1[f] = mfma16(af[f], f1, a1[f]);
      a3[f] = mfma16(af[f], f3, a3[f]);
    }
  }
  asm volatile("s_waitcnt vmcnt(0)" ::: "memory");
#pragma unroll
  for (int f = 0; f < 8; f++)
#pragma unroll
    for (int ri = 0; ri < 4; ri++) {
      int r = mt + f*16 + kg*4 + ri;
      if (r < cnt) {
        float wt = sh ? 1.0f : wt_list[off + r];
        float h1 = a1[f][ri], h3 = a3[f][ri];
        float gv = h1 / (1.f + __expf(-h1)) * h3 * wt;
        gout[(size_t)(off + r) * HEXP + c0] = (ushort)rne1(gv);
      }
    }
}

// ---------------- MoE phase B: pure-DMA staging, 3-buf counted-vmcnt ---------------
// grid = (D_MODEL/128 = 8, MAXTILES). K=512, step 32, NT=16.
__global__ __launch_bounds__(256) void moe_down9(const ushort* __restrict__ gact,
    const ushort* __restrict__ sg, const float* __restrict__ w2, size_t wstride,
    const float* __restrict__ sw2, float* __restrict__ out,
    const int* __restrict__ tok_list, const int* __restrict__ counts,
    const int* __restrict__ offs, const int* __restrict__ tile2e,
    const int* __restrict__ tile2mt, const int* __restrict__ ntiles) {
  int gt = blockIdx.y;
  if (gt >= ntiles[0]) return;
  int e = tile2e[gt];
  int mt = tile2mt[gt] << 7;
  bool sh = (e == NEXP);
  int cnt = sh ? SEQ : counts[e];
  int off = sh ? 0 : offs[e];
  const float* w2p = (sh ? sw2 : w2 + (size_t)e * wstride) + (blockIdx.x << 7);
  const ushort* gin = sh ? sg : gact;
  __shared__ __align__(16) ushort A_s[3][4][128][8];
  __shared__ __align__(16) float  B_s[3][32][128];
  int tid = threadIdx.x, wv = tid >> 6, lane = tid & 63;
  int arow = lane & 15, kg = lane >> 4, akb = kg << 3;
  int c0l = wv * 32 + arow;
  int c0 = (blockIdx.x << 7) + c0l;
  int r0i = mt + lane;        if (r0i >= cnt) r0i = cnt - 1;
  int r1i = mt + 64 + lane;   if (r1i >= cnt) r1i = cnt - 1;
  const ushort* aS0 = gin + (size_t)(off + r0i) * HEXP + wv * 8;
  const ushort* aS1 = gin + (size_t)(off + r1i) * HEXP + wv * 8;
  // B: rows 8wv + 2p + lane/32, col-chunk (lane&31)^wv (16B units)
  const float* b2l = w2p + (size_t)(8 * wv + (lane >> 5)) * D_MODEL + (((lane & 31) ^ wv) << 2);
  const int NT = HEXP / 32;
  auto STAGE = [&](int b, int sidx) {
    int kk = (sidx < NT ? sidx : sidx - NT) * 32;
    gload16(aS0 + kk, &A_s[b][wv][0][0]);
    gload16(aS1 + kk, &A_s[b][wv][64][0]);
#pragma unroll
    for (int p = 0; p < 4; p++)
      gload16(b2l + (size_t)(kk + 2 * p) * D_MODEL, &B_s[b][8 * wv + 2 * p][0]);
  };
  STAGE(0, 0); STAGE(1, 1); STAGE(2, 2);
  int csA = ((((c0l >> 2) ^ kg) << 2) | (c0l & 3));
  int csB = (((((c0l + 16) >> 2) ^ kg) << 2) | (c0l & 3));
  f32x4 ac0[8], ac1[8];
#pragma unroll
  for (int f = 0; f < 8; f++) { ac0[f] = (f32x4){0.f,0.f,0.f,0.f}; ac1[f] = (f32x4){0.f,0.f,0.f,0.f}; }
  for (int s = 0; s < NT; ++s) {
    int b = s % 3;
    asm volatile("s_waitcnt vmcnt(12)" ::: "memory");
    __builtin_amdgcn_s_barrier();
    bf16x8 af[8];
#pragma unroll
    for (int f = 0; f < 8; f++) af[f] = *(const bf16x8*)&A_s[b][kg][f*16 + arow][0];
    float v0[8], v1[8];
#pragma unroll
    for (int j = 0; j < 8; j++) v0[j] = B_s[b][akb + j][csA];
#pragma unroll
    for (int j = 0; j < 8; j++) v1[j] = B_s[b][akb + j][csB];
    asm volatile("s_waitcnt lgkmcnt(0)" ::: "memory");
    __builtin_amdgcn_s_barrier();
    STAGE(b, s + 3);
    bf16x8 f0 = pack8(v0), f1 = pack8(v1);
#pragma unroll
    for (int f = 0; f < 8; f++) {
      ac0[f] = mfma16(af[f], f0, ac0[f]);
      ac1[f] = mfma16(af[f], f1, ac1[f]);
    }
  }
  asm volatile("s_waitcnt vmcnt(0)" ::: "memory");
#pragma unroll
  for (int f = 0; f < 8; f++)
#pragma unroll
    for (int ri = 0; ri < 4; ri++) {
      int r = mt + f*16 + kg*4 + ri;
      if (r < cnt) {
        int tok = sh ? r : tok_list[off + r];
        float* op = out + (size_t)tok * D_MODEL + c0;
        atomicAdd(op, ac0[f][ri]);
        atomicAdd(op + 16, ac1[f][ri]);
      }
    }
}

// ---------------- host ----------------
extern "C" void kernel_launch(void* const* d_in, const int* in_sizes, int n_in,
                              void* d_out, int out_size, void* d_ws, size_t ws_size,
                              hipStream_t stream) {
  const float* x     = (const float*)d_in[0];
  const float* fcos  = (const float*)d_in[1];
  const float* fsin  = (const float*)d_in[2];
  const float* anw   = (const float*)d_in[3];
  const float* fnw   = (const float*)d_in[4];
  const float* wq    = (const float*)d_in[5];
  const float* wk    = (const float*)d_in[6];
  const float* wvv   = (const float*)d_in[7];
  const float* wo    = (const float*)d_in[8];
  const float* qnw   = (const float*)d_in[9];
  const float* knw   = (const float*)d_in[10];
  const float* gatew = (const float*)d_in[11];
  const float* w1e   = (const float*)d_in[12];
  const float* w3e   = (const float*)d_in[13];
  const float* w2e   = (const float*)d_in[14];
  const float* sw1   = (const float*)d_in[15];
  const float* sw3   = (const float*)d_in[16];
  const float* sw2   = (const float*)d_in[17];
  float* out = (float*)d_out;

  char* ws = (char*)d_ws;
  const size_t MB = 1ull << 20;
  float*  hx    = (float*)(ws);             // 4MB (attn-norm out, then attn out)
  float*  h     = (float*)(ws + 4*MB);      // 4MB residual after attention
  float*  z     = (float*)(ws + 8*MB);      // 4MB ffn-norm out (f32, for gate)
  float*  qbuf  = (float*)(ws + 12*MB);     // 4MB   (dead after attention)
  float*  kbuf  = (float*)(ws + 16*MB);     // 1MB
  float*  vbuf  = (float*)(ws + 17*MB);     // 1MB
  ushort* zb    = (ushort*)(ws + 12*MB);    // 2MB bf16 z (overlaps dead qbuf)
  ushort* gb    = (ushort*)(ws + 14*MB);    // 6.3MB bf16 expert activations
  ushort* s_gb  = (ushort*)(ws + 20*MB + 512*1024); // 1MB shared-expert act
  char*   misc  = ws + 22*MB;
  int*   sel      = (int*)(misc);
  float* topw     = (float*)(misc + 24576);
  int*   counts   = (int*)(misc + 49152);
  int*   offs     = (int*)(misc + 49408);
  int*   cursor   = (int*)(misc + 49664);
  int*   ntiles   = (int*)(misc + 50432);
  int*   tile2e   = (int*)(misc + 50688);
  int*   tile2mt  = (int*)(misc + 51200);
  int*   tok_list = (int*)(misc + 51712);
  float* wt_list  = (float*)(misc + 76288);

  // 1. attn rmsnorm
  rmsnorm_k<<<SEQ, 256, 0, stream>>>(x, anw, hx, nullptr);
  // 2. QKV projections (split-bf16 MFMA, relaxed-barrier pipeline)
  mfma_gemm_k<<<dim3(8, 64), 256, 0, stream>>>(hx, wq, qbuf, nullptr, nullptr, 1024, 1024);
  mfma_gemm_k<<<dim3(2, 64), 256, 0, stream>>>(hx, wk, kbuf, nullptr, nullptr, 256, 1024);
  mfma_gemm_k<<<dim3(2, 64), 256, 0, stream>>>(hx, wvv, vbuf, nullptr, nullptr, 256, 1024);
  // 3. q/k rmsnorm + rope
  qknorm_rope_k<<<dim3(SEQ, NHEADS + NKVH), 64, 0, stream>>>(qbuf, kbuf, qnw, knw, fcos, fsin);
  // 4. causal flash attention (bf16 MFMA) -> hx
  attn_mfma<<<dim3(SEQ / 64, NHEADS), 256, 0, stream>>>(qbuf, kbuf, vbuf, hx);
  // 5. o @ wo + x -> h (and d_out = h)
  mfma_gemm_k<<<dim3(8, 64), 256, 0, stream>>>(hx, wo, h, out, x, 1024, 1024);
  // 6. ffn rmsnorm -> z (f32) + zb (bf16)
  rmsnorm_k<<<SEQ, 256, 0, stream>>>(h, fnw, z, zb);
  // 7. gate + top-k + bucketing + flattened tile list (incl. shared tiles)
  hipMemsetAsync(counts, 0, 256, stream);
  gate_topk_k<<<SEQ, 64, 0, stream>>>(z, gatew, sel, topw, counts);
  scan_k<<<1, 64, 0, stream>>>(counts, offs, cursor, tile2e, tile2mt, ntiles);
  scatter_k<<<SEQ / 256, 256, 0, stream>>>(sel, topw, cursor, tok_list, wt_list);
  // 8. MoE phase A (experts + shared expert in one dispatch)
  moe_up9<<<dim3(HEXP / 64, MAXTILES), 256, 0, stream>>>(zb, w1e, w3e,
      (size_t)D_MODEL * HEXP, sw1, sw3, gb, s_gb, tok_list, wt_list,
      counts, offs, tile2e, tile2mt, ntiles);
  // 9. MoE phase B (experts + shared expert in one dispatch)
  moe_down9<<<dim3(D_MODEL / 128, MAXTILES), 256, 0, stream>>>(gb, s_gb, w2e,
      (size_t)HEXP * D_MODEL, sw2, out, tok_list, counts, offs,
      tile2e, tile2mt, ntiles);
  (void)in_sizes; (void)n_in; (void)out_size; (void)ws_size;
}